// Round 2
// baseline (2624.534 us; speedup 1.0000x reference)
//
#include <hip/hip_runtime.h>
#include <hip/hip_bf16.h>

// 2-layer R-GCN (NUM_RELS=2), fp32.
//  N=50000 nodes, E=800000 edges, feats 64 -> 128 -> 64.
//  layer(x, W, loop, b): agg = segsum( (etype==0 ? x@W0 : x@W1)[src], dst ) + x@loop + b
//  out = layer2( relu( layer1(feat) ) )

#define N_IN   64
#define N_HID  128
#define N_OUT  64

// ---------------- node transform: Y[n,c] = sum_k X[n,k]*M[k,c] (+bias) ----------------
template <int K, int C>
__global__ void transform_kernel(const float* __restrict__ X,   // [N,K]
                                 const float* __restrict__ M,   // [K,C]
                                 const float* __restrict__ bias,// [C] or nullptr
                                 float* __restrict__ Y,         // [N,C]
                                 int N) {
    __shared__ float sM[K * C];
    for (int i = threadIdx.x; i < K * C; i += blockDim.x) sM[i] = M[i];
    __syncthreads();

    int total = N * C;
    for (int idx = blockIdx.x * blockDim.x + threadIdx.x; idx < total;
         idx += gridDim.x * blockDim.x) {
        int n = idx >> __builtin_ctz(C);   // idx / C (C power of 2)
        int c = idx & (C - 1);
        const float* xr = X + n * K;
        float acc = bias ? bias[c] : 0.0f;
#pragma unroll
        for (int k = 0; k < K; ++k) acc += xr[k] * sM[k * C + c];
        Y[idx] = acc;
    }
}

// ---------------- edge scatter: agg[dst] += (etype==0 ? X0 : X1)[src] ----------------
template <int C>
__global__ void scatter_kernel(const float* __restrict__ X0,
                               const float* __restrict__ X1,
                               const int* __restrict__ src,
                               const int* __restrict__ dst,
                               const int* __restrict__ et,
                               float* __restrict__ agg,
                               int E) {
    constexpr int VEC = 4;
    constexpr int TPE = C / VEC;     // threads per edge (power of 2)
    int total = E * TPE;
    for (int idx = blockIdx.x * blockDim.x + threadIdx.x; idx < total;
         idx += gridDim.x * blockDim.x) {
        int e = idx >> __builtin_ctz(TPE);
        int t = idx & (TPE - 1);
        int s = src[e];
        int d = dst[e];
        const float* xs = (et[e] == 0 ? X0 : X1) + (long)s * C + t * VEC;
        float4 v = *reinterpret_cast<const float4*>(xs);
        float* ad = agg + (long)d * C + t * VEC;
        atomicAdd(ad + 0, v.x);
        atomicAdd(ad + 1, v.y);
        atomicAdd(ad + 2, v.z);
        atomicAdd(ad + 3, v.w);
    }
}

// ---------------- relu in place ----------------
__global__ void relu_kernel(float* __restrict__ x, int n) {
    for (int i = blockIdx.x * blockDim.x + threadIdx.x; i < n;
         i += gridDim.x * blockDim.x) {
        float v = x[i];
        x[i] = v > 0.0f ? v : 0.0f;
    }
}

extern "C" void kernel_launch(void* const* d_in, const int* in_sizes, int n_in,
                              void* d_out, int out_size, void* d_ws, size_t ws_size,
                              hipStream_t stream) {
    const float* feat  = (const float*)d_in[0];   // [N,64]
    const float* W1    = (const float*)d_in[1];   // [2,64,128]
    const float* loop1 = (const float*)d_in[2];   // [64,128]
    const float* b1    = (const float*)d_in[3];   // [128]
    const float* W2    = (const float*)d_in[4];   // [2,128,64]
    const float* loop2 = (const float*)d_in[5];   // [128,64]
    const float* b2    = (const float*)d_in[6];   // [64]
    const int*   src   = (const int*)d_in[7];     // [E]
    const int*   dst   = (const int*)d_in[8];     // [E]
    const int*   et    = (const int*)d_in[9];     // [E]
    float*       out   = (float*)d_out;           // [N,64]

    const int N = in_sizes[0] / N_IN;
    const int E = in_sizes[7];

    float* ws = (float*)d_ws;
    float* x0 = ws;                        // [N,128] (layer2 reuses as [N,64])
    float* x1 = ws + (size_t)N * N_HID;    // [N,128] (layer2 reuses as [N,64])
    float* h  = ws + (size_t)2 * N * N_HID;// [N,128]

    const int BLK = 256;
    const int gT1 = min((N * N_HID + BLK - 1) / BLK, 8192);
    const int gT2 = min((N * N_OUT + BLK - 1) / BLK, 8192);
    const int gS1 = min((E * (N_HID / 4) + BLK - 1) / BLK, 8192);
    const int gS2 = min((E * (N_OUT / 4) + BLK - 1) / BLK, 8192);

    // ---- layer 1 ----
    transform_kernel<N_IN, N_HID><<<gT1, BLK, 0, stream>>>(feat, W1, nullptr, x0, N);
    transform_kernel<N_IN, N_HID><<<gT1, BLK, 0, stream>>>(feat, W1 + N_IN * N_HID, nullptr, x1, N);
    transform_kernel<N_IN, N_HID><<<gT1, BLK, 0, stream>>>(feat, loop1, b1, h, N);   // agg init
    scatter_kernel<N_HID><<<gS1, BLK, 0, stream>>>(x0, x1, src, dst, et, h, E);
    relu_kernel<<<gT1, BLK, 0, stream>>>(h, N * N_HID);

    // ---- layer 2 ----
    transform_kernel<N_HID, N_OUT><<<gT2, BLK, 0, stream>>>(h, W2, nullptr, x0, N);
    transform_kernel<N_HID, N_OUT><<<gT2, BLK, 0, stream>>>(h, W2 + N_HID * N_OUT, nullptr, x1, N);
    transform_kernel<N_HID, N_OUT><<<gT2, BLK, 0, stream>>>(h, loop2, b2, out, N);   // agg init
    scatter_kernel<N_OUT><<<gS2, BLK, 0, stream>>>(x0, x1, src, dst, et, out, E);
}

// Round 3
// 935.728 us; speedup vs baseline: 2.8048x; 2.8048x over previous
//
#include <hip/hip_runtime.h>
#include <hip/hip_bf16.h>

// 2-layer R-GCN (NUM_RELS=2), fp32, atomic-free via per-launch dst-CSR.
//  N=50000, E=800000, feats 64 -> 128 -> 64.
//  layer(x,W,loop,b): agg = segsum((etype==0 ? x@W0 : x@W1)[src], dst) + x@loop + b
//  out = layer2(relu(layer1(feat)))

#define N_IN   64
#define N_HID  128
#define N_OUT  64

// ---------------- CSR build ----------------
__global__ void hist_kernel(const int* __restrict__ dst, int* __restrict__ cnt, int E) {
    for (int e = blockIdx.x * blockDim.x + threadIdx.x; e < E;
         e += gridDim.x * blockDim.x)
        atomicAdd(&cnt[dst[e]], 1);
}

// single-block exclusive scan of cnt[0..N) -> off[0..N], also copies to cur[]
__global__ void scan_kernel(const int* __restrict__ cnt, int* __restrict__ off,
                            int* __restrict__ cur, int N) {
    __shared__ int buf[1024];
    __shared__ int carry;
    if (threadIdx.x == 0) carry = 0;
    __syncthreads();
    for (int base = 0; base < N; base += 1024) {
        int i = base + (int)threadIdx.x;
        int v = (i < N) ? cnt[i] : 0;
        buf[threadIdx.x] = v;
        __syncthreads();
        // Hillis-Steele inclusive scan over 1024
        for (int s = 1; s < 1024; s <<= 1) {
            int t = (threadIdx.x >= (unsigned)s) ? buf[threadIdx.x - s] : 0;
            __syncthreads();
            buf[threadIdx.x] += t;
            __syncthreads();
        }
        int excl = buf[threadIdx.x] - v;
        if (i < N) {
            off[i] = carry + excl;
            cur[i] = carry + excl;
        }
        __syncthreads();
        if (threadIdx.x == 0) carry += buf[1023];
        __syncthreads();
    }
    if (threadIdx.x == 0) off[N] = carry;
}

__global__ void fill_kernel(const int* __restrict__ src, const int* __restrict__ dst,
                            const int* __restrict__ et, int* __restrict__ cur,
                            int* __restrict__ ent, int E) {
    for (int e = blockIdx.x * blockDim.x + threadIdx.x; e < E;
         e += gridDim.x * blockDim.x) {
        int pos = atomicAdd(&cur[dst[e]], 1);
        ent[pos] = (src[e] << 1) | et[e];
    }
}

// ---------------- node transforms ----------------
// Y[n,c] = sum_k X[n,k]*M[k,c] + bias[c]   (single matrix, with bias)
template <int K, int C>
__global__ void transform_kernel(const float* __restrict__ X,
                                 const float* __restrict__ M,
                                 const float* __restrict__ bias,
                                 float* __restrict__ Y, int N) {
    __shared__ float sM[K * C];
    for (int i = threadIdx.x; i < K * C; i += blockDim.x) sM[i] = M[i];
    __syncthreads();
    int total = N * C;
    for (int idx = blockIdx.x * blockDim.x + threadIdx.x; idx < total;
         idx += gridDim.x * blockDim.x) {
        int n = idx >> __builtin_ctz(C);
        int c = idx & (C - 1);
        const float* xr = X + (size_t)n * K;
        float acc = bias ? bias[c] : 0.0f;
#pragma unroll
        for (int k = 0; k < K; ++k) acc += xr[k] * sM[k * C + c];
        Y[idx] = acc;
    }
}

// Y0 = X@M0, Y1 = X@M1 fused (reads X once; both weight mats LDS-resident)
template <int K, int C>
__global__ void transform2_kernel(const float* __restrict__ X,
                                  const float* __restrict__ M0,
                                  const float* __restrict__ M1,
                                  float* __restrict__ Y0,
                                  float* __restrict__ Y1, int N) {
    __shared__ float sM[2 * K * C];   // 64 KB for both shapes here
    for (int i = threadIdx.x; i < K * C; i += blockDim.x) {
        sM[i]         = M0[i];
        sM[K * C + i] = M1[i];
    }
    __syncthreads();
    int total = N * C;
    for (int idx = blockIdx.x * blockDim.x + threadIdx.x; idx < total;
         idx += gridDim.x * blockDim.x) {
        int n = idx >> __builtin_ctz(C);
        int c = idx & (C - 1);
        const float* xr = X + (size_t)n * K;
        float a0 = 0.0f, a1 = 0.0f;
#pragma unroll
        for (int k = 0; k < K; ++k) {
            float x = xr[k];
            a0 += x * sM[k * C + c];
            a1 += x * sM[K * C + k * C + c];
        }
        Y0[idx] = a0;
        Y1[idx] = a1;
    }
}

// ---------------- gather-aggregate (atomic-free) ----------------
// io[n,:] starts as loop-term + bias; add sum over in-edges of x{et}[src];
// optional ReLU. One 64-lane wave per node. In-place safe (own row only).
template <int C, bool RELU>
__global__ void gather_agg_kernel(const float* __restrict__ x0,
                                  const float* __restrict__ x1,
                                  const int* __restrict__ off,
                                  const int* __restrict__ ent,
                                  float* __restrict__ io, int N) {
    constexpr int FPL = C / 64;  // floats per lane (2 for C=128, 1 for C=64)
    int wid  = (int)((blockIdx.x * blockDim.x + threadIdx.x) >> 6);
    int lane = threadIdx.x & 63;
    if (wid >= N) return;
    float acc[FPL];
    float* iorow = io + (size_t)wid * C + lane * FPL;
#pragma unroll
    for (int f = 0; f < FPL; ++f) acc[f] = iorow[f];
    int e0 = off[wid], e1 = off[wid + 1];
    for (int j = e0; j < e1; ++j) {
        int p = ent[j];
        const float* row = ((p & 1) ? x1 : x0) + (size_t)(p >> 1) * C + lane * FPL;
#pragma unroll
        for (int f = 0; f < FPL; ++f) acc[f] += row[f];
    }
#pragma unroll
    for (int f = 0; f < FPL; ++f) iorow[f] = RELU ? fmaxf(acc[f], 0.0f) : acc[f];
}

extern "C" void kernel_launch(void* const* d_in, const int* in_sizes, int n_in,
                              void* d_out, int out_size, void* d_ws, size_t ws_size,
                              hipStream_t stream) {
    const float* feat  = (const float*)d_in[0];   // [N,64]
    const float* W1    = (const float*)d_in[1];   // [2,64,128]
    const float* loop1 = (const float*)d_in[2];   // [64,128]
    const float* b1    = (const float*)d_in[3];   // [128]
    const float* W2    = (const float*)d_in[4];   // [2,128,64]
    const float* loop2 = (const float*)d_in[5];   // [128,64]
    const float* b2    = (const float*)d_in[6];   // [64]
    const int*   src   = (const int*)d_in[7];     // [E]
    const int*   dst   = (const int*)d_in[8];     // [E]
    const int*   et    = (const int*)d_in[9];     // [E]
    float*       out   = (float*)d_out;           // [N,64]

    const int N = in_sizes[0] / N_IN;
    const int E = in_sizes[7];

    // ---- workspace layout ----
    char* wsb = (char*)d_ws;
    int* cnt = (int*)wsb;                 // [N]
    int* off = cnt + N;                   // [N+1]
    int* cur = off + (N + 1);             // [N]
    int* ent = cur + N;                   // [E]
    size_t int_bytes = ((size_t)(3 * N + 1 + E) * sizeof(int) + 255) & ~(size_t)255;
    float* x0 = (float*)(wsb + int_bytes);        // [N,128] (layer2: [N,64])
    float* x1 = x0 + (size_t)N * N_HID;           // [N,128] (layer2: [N,64])
    float* h  = x1 + (size_t)N * N_HID;           // [N,128] base -> relu'd h in place

    const int BLK = 256;
    const int gE   = min((E + BLK - 1) / BLK, 2048);
    const int gT1  = min((N * N_HID + BLK - 1) / BLK, 8192);
    const int gT2  = min((N * N_OUT + BLK - 1) / BLK, 8192);
    const int gAgg = (N * 64 + BLK - 1) / BLK;   // one wave per node

    // ---- CSR build (shared by both layers) ----
    hipMemsetAsync(cnt, 0, (size_t)N * sizeof(int), stream);
    hist_kernel<<<gE, BLK, 0, stream>>>(dst, cnt, E);
    scan_kernel<<<1, 1024, 0, stream>>>(cnt, off, cur, N);
    fill_kernel<<<gE, BLK, 0, stream>>>(src, dst, et, cur, ent, E);

    // ---- layer 1 ----
    transform2_kernel<N_IN, N_HID><<<gT1, BLK, 0, stream>>>(
        feat, W1, W1 + N_IN * N_HID, x0, x1, N);
    transform_kernel<N_IN, N_HID><<<gT1, BLK, 0, stream>>>(feat, loop1, b1, h, N);
    gather_agg_kernel<N_HID, true><<<gAgg, BLK, 0, stream>>>(x0, x1, off, ent, h, N);

    // ---- layer 2 ----
    transform2_kernel<N_HID, N_OUT><<<gT2, BLK, 0, stream>>>(
        h, W2, W2 + N_HID * N_OUT, x0, x1, N);
    transform_kernel<N_HID, N_OUT><<<gT2, BLK, 0, stream>>>(h, loop2, b2, out, N);
    gather_agg_kernel<N_OUT, false><<<gAgg, BLK, 0, stream>>>(x0, x1, off, ent, out, N);
}

// Round 4
// 579.588 us; speedup vs baseline: 4.5283x; 1.6145x over previous
//
#include <hip/hip_runtime.h>
#include <hip/hip_bf16.h>

// 2-layer R-GCN (NUM_RELS=2), fp32, atomic-free dst-CSR + tiled-GEMM transforms.
//  N=50000, E=800000, feats 64 -> 128 -> 64.
//  layer(x,W,loop,b): agg = segsum((etype==0 ? x@W0 : x@W1)[src], dst) + x@loop + b
//  out = layer2(relu(layer1(feat)))

#define N_IN   64
#define N_HID  128
#define N_OUT  64

// ---------------- CSR build ----------------
__global__ void hist_kernel(const int* __restrict__ dst, int* __restrict__ cnt, int E) {
    for (int e = blockIdx.x * blockDim.x + threadIdx.x; e < E;
         e += gridDim.x * blockDim.x)
        atomicAdd(&cnt[dst[e]], 1);
}

// single-block exclusive scan of cnt[0..N) -> off[0..N], also copies to cur[]
__global__ void scan_kernel(const int* __restrict__ cnt, int* __restrict__ off,
                            int* __restrict__ cur, int N) {
    __shared__ int buf[1024];
    __shared__ int carry;
    if (threadIdx.x == 0) carry = 0;
    __syncthreads();
    for (int base = 0; base < N; base += 1024) {
        int i = base + (int)threadIdx.x;
        int v = (i < N) ? cnt[i] : 0;
        buf[threadIdx.x] = v;
        __syncthreads();
        for (int s = 1; s < 1024; s <<= 1) {
            int t = (threadIdx.x >= (unsigned)s) ? buf[threadIdx.x - s] : 0;
            __syncthreads();
            buf[threadIdx.x] += t;
            __syncthreads();
        }
        int excl = buf[threadIdx.x] - v;
        if (i < N) {
            off[i] = carry + excl;
            cur[i] = carry + excl;
        }
        __syncthreads();
        if (threadIdx.x == 0) carry += buf[1023];
        __syncthreads();
    }
    if (threadIdx.x == 0) off[N] = carry;
}

__global__ void fill_kernel(const int* __restrict__ src, const int* __restrict__ dst,
                            const int* __restrict__ et, int* __restrict__ cur,
                            int* __restrict__ ent, int E) {
    for (int e = blockIdx.x * blockDim.x + threadIdx.x; e < E;
         e += gridDim.x * blockDim.x) {
        int pos = atomicAdd(&cur[dst[e]], 1);
        ent[pos] = (src[e] << 1) | et[e];
    }
}

// ---------------- fused node transform: tiled GEMM over [W0|W1|loop] ----------------
// Computes x0 = X@W0, x1 = X@W1, base = X@loop + bias in one GEMM of shape
// [M x KTOT] @ [KTOT x 3C]. Each BN=64 column tile lies entirely inside one
// source matrix (C is a multiple of 64), so source/dest select is block-uniform.
// BM=BN=BK=64, 256 threads, 4x4 register micro-tile per thread.
template <int KTOT, int C>
__global__ __launch_bounds__(256) void fused_transform_kernel(
    const float* __restrict__ X,      // [M,KTOT]
    const float* __restrict__ W,      // [2,KTOT,C]  (rel 0 then rel 1)
    const float* __restrict__ loopw,  // [KTOT,C]
    const float* __restrict__ bias,   // [C]
    float* __restrict__ x0, float* __restrict__ x1, float* __restrict__ base,
    int M) {
    constexpr int BM = 64, BN = 64, BK = 64, PAD = 4;
    __shared__ float Xs[BM][BK + PAD];
    __shared__ float Ws[BK][BN + PAD];

    const int tid  = threadIdx.x;
    const int row0 = blockIdx.x * BM;
    const int bn   = blockIdx.y;
    const int jg0  = bn * BN;            // global col in concatenated [3C]
    const int sec  = jg0 / C;            // 0 -> W0, 1 -> W1, 2 -> loop
    const int cof  = jg0 % C;
    const float* Wsrc = (sec < 2) ? (W + (size_t)sec * KTOT * C) : loopw;

    const int ty = tid >> 4;             // 0..15 -> 4 output rows each
    const int tx = tid & 15;             // 0..15 -> 4 output cols each

    float acc[4][4] = {};

    for (int k0 = 0; k0 < KTOT; k0 += BK) {
        // stage X tile [BM x BK] (float4, coalesced; guard M)
#pragma unroll
        for (int i = 0; i < 4; ++i) {
            int f = tid + i * 256;       // float4 slot
            int r = f >> 4;
            int c = (f & 15) << 2;
            float4 v = make_float4(0.f, 0.f, 0.f, 0.f);
            int gr = row0 + r;
            if (gr < M)
                v = *reinterpret_cast<const float4*>(X + (size_t)gr * KTOT + k0 + c);
            *reinterpret_cast<float4*>(&Xs[r][c]) = v;
        }
        // stage W tile [BK x BN]
#pragma unroll
        for (int i = 0; i < 4; ++i) {
            int f = tid + i * 256;
            int r = f >> 4;
            int c = (f & 15) << 2;
            float4 v = *reinterpret_cast<const float4*>(
                Wsrc + (size_t)(k0 + r) * C + cof + c);
            *reinterpret_cast<float4*>(&Ws[r][c]) = v;
        }
        __syncthreads();

#pragma unroll
        for (int kk = 0; kk < BK; ++kk) {
            float xv[4];
#pragma unroll
            for (int i = 0; i < 4; ++i) xv[i] = Xs[ty * 4 + i][kk];
            float4 w4 = *reinterpret_cast<const float4*>(&Ws[kk][tx * 4]);
            acc[0][0] += xv[0] * w4.x; acc[0][1] += xv[0] * w4.y;
            acc[0][2] += xv[0] * w4.z; acc[0][3] += xv[0] * w4.w;
            acc[1][0] += xv[1] * w4.x; acc[1][1] += xv[1] * w4.y;
            acc[1][2] += xv[1] * w4.z; acc[1][3] += xv[1] * w4.w;
            acc[2][0] += xv[2] * w4.x; acc[2][1] += xv[2] * w4.y;
            acc[2][2] += xv[2] * w4.z; acc[2][3] += xv[2] * w4.w;
            acc[3][0] += xv[3] * w4.x; acc[3][1] += xv[3] * w4.y;
            acc[3][2] += xv[3] * w4.z; acc[3][3] += xv[3] * w4.w;
        }
        __syncthreads();
    }

    float* outp = (sec == 0) ? x0 : (sec == 1) ? x1 : base;
#pragma unroll
    for (int i = 0; i < 4; ++i) {
        int gr = row0 + ty * 4 + i;
        if (gr >= M) continue;
        int gc = cof + tx * 4;
        float4 v = make_float4(acc[i][0], acc[i][1], acc[i][2], acc[i][3]);
        if (sec == 2) {
            v.x += bias[gc]; v.y += bias[gc + 1];
            v.z += bias[gc + 2]; v.w += bias[gc + 3];
        }
        *reinterpret_cast<float4*>(outp + (size_t)gr * C + gc) = v;
    }
}

// ---------------- gather-aggregate (atomic-free) ----------------
// io[n,:] starts as loop-term + bias; add sum over in-edges of x{et}[src];
// optional ReLU. One 64-lane wave per node. In-place safe (own row only).
template <int C, bool RELU>
__global__ void gather_agg_kernel(const float* __restrict__ x0,
                                  const float* __restrict__ x1,
                                  const int* __restrict__ off,
                                  const int* __restrict__ ent,
                                  float* __restrict__ io, int N) {
    constexpr int FPL = C / 64;  // floats per lane
    int wid  = (int)((blockIdx.x * blockDim.x + threadIdx.x) >> 6);
    int lane = threadIdx.x & 63;
    if (wid >= N) return;
    float acc[FPL];
    float* iorow = io + (size_t)wid * C + lane * FPL;
#pragma unroll
    for (int f = 0; f < FPL; ++f) acc[f] = iorow[f];
    int e0 = off[wid], e1 = off[wid + 1];
    for (int j = e0; j < e1; ++j) {
        int p = ent[j];
        const float* row = ((p & 1) ? x1 : x0) + (size_t)(p >> 1) * C + lane * FPL;
#pragma unroll
        for (int f = 0; f < FPL; ++f) acc[f] += row[f];
    }
#pragma unroll
    for (int f = 0; f < FPL; ++f) iorow[f] = RELU ? fmaxf(acc[f], 0.0f) : acc[f];
}

extern "C" void kernel_launch(void* const* d_in, const int* in_sizes, int n_in,
                              void* d_out, int out_size, void* d_ws, size_t ws_size,
                              hipStream_t stream) {
    const float* feat  = (const float*)d_in[0];   // [N,64]
    const float* W1    = (const float*)d_in[1];   // [2,64,128]
    const float* loop1 = (const float*)d_in[2];   // [64,128]
    const float* b1    = (const float*)d_in[3];   // [128]
    const float* W2    = (const float*)d_in[4];   // [2,128,64]
    const float* loop2 = (const float*)d_in[5];   // [128,64]
    const float* b2    = (const float*)d_in[6];   // [64]
    const int*   src   = (const int*)d_in[7];     // [E]
    const int*   dst   = (const int*)d_in[8];     // [E]
    const int*   et    = (const int*)d_in[9];     // [E]
    float*       out   = (float*)d_out;           // [N,64]

    const int N = in_sizes[0] / N_IN;
    const int E = in_sizes[7];

    // ---- workspace layout ----
    char* wsb = (char*)d_ws;
    int* cnt = (int*)wsb;                 // [N]
    int* off = cnt + N;                   // [N+1]
    int* cur = off + (N + 1);             // [N]
    int* ent = cur + N;                   // [E]
    size_t int_bytes = ((size_t)(3 * N + 1 + E) * sizeof(int) + 255) & ~(size_t)255;
    float* x0 = (float*)(wsb + int_bytes);        // [N,128] (layer2: [N,64])
    float* x1 = x0 + (size_t)N * N_HID;           // [N,128] (layer2: [N,64])
    float* h  = x1 + (size_t)N * N_HID;           // [N,128] base -> relu'd h in place

    const int BLK  = 256;
    const int gE   = min((E + BLK - 1) / BLK, 2048);
    const int gAgg = (N * 64 + BLK - 1) / BLK;    // one wave per node
    const int mT   = (N + 63) / 64;               // GEMM row tiles

    // ---- CSR build (shared by both layers) ----
    hipMemsetAsync(cnt, 0, (size_t)N * sizeof(int), stream);
    hist_kernel<<<gE, BLK, 0, stream>>>(dst, cnt, E);
    scan_kernel<<<1, 1024, 0, stream>>>(cnt, off, cur, N);
    fill_kernel<<<gE, BLK, 0, stream>>>(src, dst, et, cur, ent, E);

    // ---- layer 1: x0|x1|h = feat @ [W0|W1|loop1](+b1) ----
    fused_transform_kernel<N_IN, N_HID><<<dim3(mT, 3 * N_HID / 64), BLK, 0, stream>>>(
        feat, W1, loop1, b1, x0, x1, h, N);
    gather_agg_kernel<N_HID, true><<<gAgg, BLK, 0, stream>>>(x0, x1, off, ent, h, N);

    // ---- layer 2 ----
    fused_transform_kernel<N_HID, N_OUT><<<dim3(mT, 3 * N_OUT / 64), BLK, 0, stream>>>(
        h, W2, loop2, b2, x0, x1, out, N);
    gather_agg_kernel<N_OUT, false><<<gAgg, BLK, 0, stream>>>(x0, x1, off, ent, out, N);
}

// Round 7
// 372.651 us; speedup vs baseline: 7.0429x; 1.5553x over previous
//
#include <hip/hip_runtime.h>
#include <hip/hip_bf16.h>

// 2-layer R-GCN (NUM_RELS=2). bf16 MFMA transforms + bf16 gather pipeline,
// fp32 accumulation everywhere. Atomic-free dst-CSR with parallel scan.
//  N=50000, E=800000, feats 64 -> 128 -> 64.
//  layer(x,W,loop,b): agg = segsum((etype==0 ? x@W0 : x@W1)[src], dst) + x@loop + b
//  out = layer2(relu(layer1(feat)))

#define N_IN   64
#define N_HID  128
#define N_OUT  64

typedef __attribute__((ext_vector_type(8))) short  bf16x8;
typedef __attribute__((ext_vector_type(4))) float  f32x4;

__device__ __forceinline__ ushort f2bf(float f) {   // RNE
    uint u = __float_as_uint(f);
    u += 0x7FFFu + ((u >> 16) & 1u);
    return (ushort)(u >> 16);
}
__device__ __forceinline__ float bf2f(ushort h) {
    return __uint_as_float(((uint)h) << 16);
}

// ---------------- CSR build ----------------
__global__ void hist_kernel(const int* __restrict__ dst, int* __restrict__ cnt, int E) {
    for (int e = blockIdx.x * blockDim.x + threadIdx.x; e < E;
         e += gridDim.x * blockDim.x)
        atomicAdd(&cnt[dst[e]], 1);
}

__global__ void scan_reduce_kernel(const int* __restrict__ cnt, int* __restrict__ bsum, int N) {
    __shared__ int s[1024];
    int i = blockIdx.x * 1024 + threadIdx.x;
    s[threadIdx.x] = (i < N) ? cnt[i] : 0;
    __syncthreads();
    for (int st = 512; st > 0; st >>= 1) {
        if ((int)threadIdx.x < st) s[threadIdx.x] += s[threadIdx.x + st];
        __syncthreads();
    }
    if (threadIdx.x == 0) bsum[blockIdx.x] = s[0];
}

// 64-thread exclusive scan of bsum[0..NB) (NB <= 64); total -> *offN
__global__ void scan_top_kernel(const int* __restrict__ bsum, int* __restrict__ bx,
                                int NB, int* __restrict__ offN) {
    int l = threadIdx.x;
    int v = (l < NB) ? bsum[l] : 0;
    int x = v;
    for (int s = 1; s < 64; s <<= 1) {
        int t = __shfl_up(x, (unsigned)s, 64);
        if (l >= s) x += t;
    }
    if (l < NB) bx[l] = x - v;
    if (l == 63) *offN = x;
}

__global__ void scan_block_kernel(const int* __restrict__ cnt, const int* __restrict__ bx,
                                  int* __restrict__ off, int* __restrict__ cur, int N) {
    __shared__ int s[1024];
    int i = blockIdx.x * 1024 + threadIdx.x;
    int v = (i < N) ? cnt[i] : 0;
    s[threadIdx.x] = v;
    __syncthreads();
    for (int st = 1; st < 1024; st <<= 1) {
        int t = ((int)threadIdx.x >= st) ? s[threadIdx.x - st] : 0;
        __syncthreads();
        s[threadIdx.x] += t;
        __syncthreads();
    }
    if (i < N) {
        int e = bx[blockIdx.x] + s[threadIdx.x] - v;
        off[i] = e;
        cur[i] = e;
    }
}

__global__ void fill_kernel(const int* __restrict__ src, const int* __restrict__ dst,
                            const int* __restrict__ et, int* __restrict__ cur,
                            int* __restrict__ ent, int E) {
    for (int e = blockIdx.x * blockDim.x + threadIdx.x; e < E;
         e += gridDim.x * blockDim.x) {
        int pos = atomicAdd(&cur[dst[e]], 1);
        ent[pos] = (src[e] << 1) | et[e];
    }
}

// ---------------- fp32 -> bf16 converts ----------------
__global__ void cvt_f32_bf16_kernel(const float* __restrict__ in,
                                    ushort* __restrict__ out, int n4) {
    for (int i = blockIdx.x * blockDim.x + threadIdx.x; i < n4;
         i += gridDim.x * blockDim.x) {
        float4 v = reinterpret_cast<const float4*>(in)[i];
        ushort4 o;
        o.x = f2bf(v.x); o.y = f2bf(v.y); o.z = f2bf(v.z); o.w = f2bf(v.w);
        reinterpret_cast<ushort4*>(out)[i] = o;
    }
}

// Convert [W0|W1|loop] (fp32, row-major [KTOT x C] each) into bf16
// FRAGMENT-MAJOR panels for mfma_f32_16x16x32_bf16 B-operand:
// panel p = (sec*C+col)/64; within panel: idx = ((n16*(KTOT/8)+k/8)*16 + c)*8 + k%8
// where cin = (sec*C+col)%64, n16 = cin/16, c = cin%16.
template <int KTOT, int C>
__global__ void cvt_weights_kernel(const float* __restrict__ W,
                                   const float* __restrict__ loopw,
                                   ushort* __restrict__ dst) {
    const int TOT = 3 * C * KTOT;
    int q = blockIdx.x * blockDim.x + threadIdx.x;
    if (q >= TOT) return;
    int k = q / (3 * C), jgc = q % (3 * C);
    int sec = jgc / C, col = jgc % C;
    float v = (sec < 2) ? W[((size_t)sec * KTOT + k) * C + col]
                        : loopw[(size_t)k * C + col];
    int p = jgc >> 6, cin = jgc & 63;
    int di = p * (64 * KTOT) +
             (((cin >> 4) * (KTOT / 8) + (k >> 3)) * 16 + (cin & 15)) * 8 + (k & 7);
    dst[di] = f2bf(v);
}

// ---------------- MFMA node transform ----------------
// Y[:, 0:3C] = X @ [W0|W1|loop](+bias on loop sec), outputs routed to
// x0/x1/baseb (all bf16). BM=128, BN=64 (one panel), full-K single pass.
// 256 threads = 4 waves in 2x2; each wave owns 64x32 of the 128x64 tile.
template <int KTOT, int C>
__global__ __launch_bounds__(256, 4) void mfma_transform_kernel(
    const ushort* __restrict__ Xb,    // [M,KTOT] bf16
    const ushort* __restrict__ Wf,    // frag-major panels [3C/64][64*KTOT]
    const float*  __restrict__ bias,  // [C]
    ushort* __restrict__ x0, ushort* __restrict__ x1, ushort* __restrict__ baseb,
    int M) {
    constexpr int CPR = KTOT / 8;     // 16B chunks per row
    constexpr int NKB = KTOT / 32;    // K steps
    __shared__ ushort Al[128 * KTOT]; // fragment-major A tile

    const int row0 = blockIdx.x * 128;
    const int by   = blockIdx.y;
    const int sec  = (by * 64) / C;
    const int cof  = (by * 64) % C;

    const int wid  = threadIdx.x >> 6;
    const int wm   = wid >> 1, wn = wid & 1;
    const int lane = threadIdx.x & 63;

    // B fragments straight from global (frag-major, L2-resident)
    const ushort* Wp = Wf + (size_t)by * (64 * KTOT);
    bf16x8 bfrag[2][NKB];
#pragma unroll
    for (int j = 0; j < 2; ++j)
#pragma unroll
        for (int kb = 0; kb < NKB; ++kb)
            bfrag[j][kb] = *reinterpret_cast<const bf16x8*>(
                Wp + ((wn * 2 + j) * CPR + kb * 4) * 128 + lane * 8);

    // stage A tile into LDS, fragment-major (zero-fill OOB rows)
    constexpr int CH = 128 * CPR;     // total 16B chunks
    for (int ch = threadIdx.x; ch < CH; ch += 256) {
        int r = ch / CPR, kk8 = ch % CPR;
        int grow = row0 + r;
        uint4 v = make_uint4(0u, 0u, 0u, 0u);
        if (grow < M)
            v = *reinterpret_cast<const uint4*>(Xb + (size_t)grow * KTOT + kk8 * 8);
        int di = (((r >> 4) * CPR + kk8) * 16 + (r & 15)) * 8;
        *reinterpret_cast<uint4*>(&Al[di]) = v;
    }
    __syncthreads();

    f32x4 acc[4][2] = {};
#pragma unroll
    for (int kb = 0; kb < NKB; ++kb) {
        bf16x8 afrag[4];
#pragma unroll
        for (int i = 0; i < 4; ++i)
            afrag[i] = *reinterpret_cast<const bf16x8*>(
                &Al[((wm * 4 + i) * CPR + kb * 4) * 128 + lane * 8]);
#pragma unroll
        for (int i = 0; i < 4; ++i)
#pragma unroll
            for (int j = 0; j < 2; ++j)
                acc[i][j] = __builtin_amdgcn_mfma_f32_16x16x32_bf16(
                    afrag[i], bfrag[j][kb], acc[i][j], 0, 0, 0);
    }

    ushort* dst = (sec == 0) ? x0 : (sec == 1) ? x1 : baseb;
#pragma unroll
    for (int i = 0; i < 4; ++i) {
        int grow0 = row0 + (wm * 4 + i) * 16 + (lane >> 4) * 4;
#pragma unroll
        for (int j = 0; j < 2; ++j) {
            int scol = cof + wn * 32 + j * 16 + (lane & 15);
            float badd = (sec == 2) ? bias[scol] : 0.0f;
#pragma unroll
            for (int jj = 0; jj < 4; ++jj) {
                int grow = grow0 + jj;
                if (grow < M)
                    dst[(size_t)grow * C + scol] = f2bf(acc[i][j][jj] + badd);
            }
        }
    }
}

// ---------------- gather-aggregate (atomic-free, bf16 tables) ----------------
// acc = baseb[n] (bf16->f32); += sum over in-edges of x{et}[src]; optional ReLU;
// write bf16 (hidden layer) or fp32 (final output). One 64-lane wave per node.
template <int C, bool RELU, bool OUTBF>
__global__ void gather_agg_kernel(const ushort* __restrict__ x0,
                                  const ushort* __restrict__ x1,
                                  const ushort* __restrict__ baseb,
                                  const int* __restrict__ off,
                                  const int* __restrict__ ent,
                                  ushort* __restrict__ outb,
                                  float* __restrict__ outf, int N) {
    constexpr int FPL = C / 64;   // 2 for C=128, 1 for C=64
    int wid  = (int)((blockIdx.x * blockDim.x + threadIdx.x) >> 6);
    int lane = threadIdx.x & 63;
    if (wid >= N) return;
    float acc[FPL];
    const ushort* bp = baseb + (size_t)wid * C + lane * FPL;
#pragma unroll
    for (int f = 0; f < FPL; ++f) acc[f] = bf2f(bp[f]);
    int e0 = off[wid], e1 = off[wid + 1];
    for (int j = e0; j < e1; ++j) {
        int p = ent[j];
        const ushort* row = ((p & 1) ? x1 : x0) + (size_t)(p >> 1) * C + lane * FPL;
        if (FPL == 2) {
            ushort2 v = *reinterpret_cast<const ushort2*>(row);
            acc[0] += bf2f(v.x);
            acc[1] += bf2f(v.y);
        } else {
            acc[0] += bf2f(row[0]);
        }
    }
#pragma unroll
    for (int f = 0; f < FPL; ++f) {
        float v = RELU ? fmaxf(acc[f], 0.0f) : acc[f];
        if (OUTBF) outb[(size_t)wid * C + lane * FPL + f] = f2bf(v);
        else       outf[(size_t)wid * C + lane * FPL + f] = v;
    }
}

extern "C" void kernel_launch(void* const* d_in, const int* in_sizes, int n_in,
                              void* d_out, int out_size, void* d_ws, size_t ws_size,
                              hipStream_t stream) {
    const float* feat  = (const float*)d_in[0];   // [N,64]
    const float* W1    = (const float*)d_in[1];   // [2,64,128]
    const float* loop1 = (const float*)d_in[2];   // [64,128]
    const float* b1    = (const float*)d_in[3];   // [128]
    const float* W2    = (const float*)d_in[4];   // [2,128,64]
    const float* loop2 = (const float*)d_in[5];   // [128,64]
    const float* b2    = (const float*)d_in[6];   // [64]
    const int*   src   = (const int*)d_in[7];     // [E]
    const int*   dst   = (const int*)d_in[8];     // [E]
    const int*   et    = (const int*)d_in[9];     // [E]
    float*       out   = (float*)d_out;           // [N,64]

    const int N = in_sizes[0] / N_IN;
    const int E = in_sizes[7];

    // ---- workspace layout ----
    char* wsb = (char*)d_ws;
    int* cnt  = (int*)wsb;            // [N]
    int* off  = cnt + N;              // [N+1]
    int* cur  = off + N + 1;          // [N]
    int* bsum = cur + N;              // [64]
    int* bx   = bsum + 64;            // [64]
    int* ent  = bx + 64;              // [E]
    size_t ibytes = (((size_t)(3 * N + 129 + E) * sizeof(int)) + 255) & ~(size_t)255;
    ushort* featb = (ushort*)(wsb + ibytes);            // [N,64]
    ushort* hb    = featb + (size_t)N * N_IN;           // [N,128]
    ushort* x0b   = hb    + (size_t)N * N_HID;          // [N,128] (L2: [N,64])
    ushort* x1b   = x0b   + (size_t)N * N_HID;          // [N,128] (L2: [N,64])
    ushort* baseb = x1b   + (size_t)N * N_HID;          // [N,128] (L2: [N,64])
    ushort* W1f   = baseb + (size_t)N * N_HID;          // [3*128*64]
    ushort* W2f   = W1f + 3 * N_HID * N_IN;             // [3*64*128]

    const int BLK  = 256;
    const int gE   = min((E + BLK - 1) / BLK, 2048);
    const int NB   = (N + 1023) / 1024;                 // scan chunks (<=64)
    const int mT   = (N + 127) / 128;                   // MFMA row tiles
    const int gAgg = (N * 64 + BLK - 1) / BLK;          // one wave per node
    const int gCvF = min((N * N_IN / 4 + BLK - 1) / BLK, 2048);

    // ---- CSR build (shared by both layers) ----
    hipMemsetAsync(cnt, 0, (size_t)N * sizeof(int), stream);
    hist_kernel<<<gE, BLK, 0, stream>>>(dst, cnt, E);
    scan_reduce_kernel<<<NB, 1024, 0, stream>>>(cnt, bsum, N);
    scan_top_kernel<<<1, 64, 0, stream>>>(bsum, bx, NB, off + N);
    scan_block_kernel<<<NB, 1024, 0, stream>>>(cnt, bx, off, cur, N);
    fill_kernel<<<gE, BLK, 0, stream>>>(src, dst, et, cur, ent, E);

    // ---- bf16 converts ----
    cvt_f32_bf16_kernel<<<gCvF, BLK, 0, stream>>>(feat, featb, N * N_IN / 4);
    cvt_weights_kernel<N_IN, N_HID><<<(3 * N_HID * N_IN + BLK - 1) / BLK, BLK, 0, stream>>>(
        W1, loop1, W1f);
    cvt_weights_kernel<N_HID, N_OUT><<<(3 * N_OUT * N_HID + BLK - 1) / BLK, BLK, 0, stream>>>(
        W2, loop2, W2f);

    // ---- layer 1 ----
    mfma_transform_kernel<N_IN, N_HID><<<dim3(mT, 3 * N_HID / 64), BLK, 0, stream>>>(
        featb, W1f, b1, x0b, x1b, baseb, N);
    gather_agg_kernel<N_HID, true, true><<<gAgg, BLK, 0, stream>>>(
        x0b, x1b, baseb, off, ent, hb, nullptr, N);

    // ---- layer 2 ----
    mfma_transform_kernel<N_HID, N_OUT><<<dim3(mT, 3 * N_OUT / 64), BLK, 0, stream>>>(
        hb, W2f, b2, x0b, x1b, baseb, N);
    gather_agg_kernel<N_OUT, false, false><<<gAgg, BLK, 0, stream>>>(
        x0b, x1b, baseb, off, ent, nullptr, out, N);
}

// Round 11
// 280.912 us; speedup vs baseline: 9.3429x; 1.3266x over previous
//
#include <hip/hip_runtime.h>
#include <hip/hip_bf16.h>

// 2-layer R-GCN (NUM_RELS=2). bf16 MFMA transforms + bf16 wide-gather pipeline,
// fp32 accumulation everywhere. Atomic-free dst-CSR with parallel scan.
//  N=50000, E=800000, feats 64 -> 128 -> 64.
//  layer(x,W,loop,b): agg = segsum((etype==0 ? x@W0 : x@W1)[src], dst) + x@loop + b
//  out = layer2(relu(layer1(feat)))

#define N_IN   64
#define N_HID  128
#define N_OUT  64

typedef __attribute__((ext_vector_type(8))) short  bf16x8;
typedef __attribute__((ext_vector_type(4))) float  f32x4;

__device__ __forceinline__ ushort f2bf(float f) {   // RNE
    uint u = __float_as_uint(f);
    u += 0x7FFFu + ((u >> 16) & 1u);
    return (ushort)(u >> 16);
}
__device__ __forceinline__ float bf2f(ushort h) {
    return __uint_as_float(((uint)h) << 16);
}
// unpack a uint holding 2 bf16: lo = bits[15:0], hi = bits[31:16]
__device__ __forceinline__ float bfu_lo(uint u) { return __uint_as_float(u << 16); }
__device__ __forceinline__ float bfu_hi(uint u) { return __uint_as_float(u & 0xFFFF0000u); }

// ---------------- CSR build ----------------
__global__ void hist_kernel(const int* __restrict__ dst, int* __restrict__ cnt, int E) {
    for (int e = blockIdx.x * blockDim.x + threadIdx.x; e < E;
         e += gridDim.x * blockDim.x)
        atomicAdd(&cnt[dst[e]], 1);
}

__global__ void scan_reduce_kernel(const int* __restrict__ cnt, int* __restrict__ bsum, int N) {
    __shared__ int s[1024];
    int i = blockIdx.x * 1024 + threadIdx.x;
    s[threadIdx.x] = (i < N) ? cnt[i] : 0;
    __syncthreads();
    for (int st = 512; st > 0; st >>= 1) {
        if ((int)threadIdx.x < st) s[threadIdx.x] += s[threadIdx.x + st];
        __syncthreads();
    }
    if (threadIdx.x == 0) bsum[blockIdx.x] = s[0];
}

// 64-thread exclusive scan of bsum[0..NB) (NB <= 64); total -> *offN
__global__ void scan_top_kernel(const int* __restrict__ bsum, int* __restrict__ bx,
                                int NB, int* __restrict__ offN) {
    int l = threadIdx.x;
    int v = (l < NB) ? bsum[l] : 0;
    int x = v;
    for (int s = 1; s < 64; s <<= 1) {
        int t = __shfl_up(x, (unsigned)s, 64);
        if (l >= s) x += t;
    }
    if (l < NB) bx[l] = x - v;
    if (l == 63) *offN = x;
}

__global__ void scan_block_kernel(const int* __restrict__ cnt, const int* __restrict__ bx,
                                  int* __restrict__ off, int* __restrict__ cur, int N) {
    __shared__ int s[1024];
    int i = blockIdx.x * 1024 + threadIdx.x;
    int v = (i < N) ? cnt[i] : 0;
    s[threadIdx.x] = v;
    __syncthreads();
    for (int st = 1; st < 1024; st <<= 1) {
        int t = ((int)threadIdx.x >= st) ? s[threadIdx.x - st] : 0;
        __syncthreads();
        s[threadIdx.x] += t;
        __syncthreads();
    }
    if (i < N) {
        int e = bx[blockIdx.x] + s[threadIdx.x] - v;
        off[i] = e;
        cur[i] = e;
    }
}

__global__ void fill_kernel(const int* __restrict__ src, const int* __restrict__ dst,
                            const int* __restrict__ et, int* __restrict__ cur,
                            int* __restrict__ ent, int E) {
    for (int e = blockIdx.x * blockDim.x + threadIdx.x; e < E;
         e += gridDim.x * blockDim.x) {
        int pos = atomicAdd(&cur[dst[e]], 1);
        ent[pos] = (src[e] << 1) | et[e];
    }
}

// ---------------- fp32 -> bf16 converts ----------------
__global__ void cvt_f32_bf16_kernel(const float* __restrict__ in,
                                    ushort* __restrict__ out, int n4) {
    for (int i = blockIdx.x * blockDim.x + threadIdx.x; i < n4;
         i += gridDim.x * blockDim.x) {
        float4 v = reinterpret_cast<const float4*>(in)[i];
        ushort4 o;
        o.x = f2bf(v.x); o.y = f2bf(v.y); o.z = f2bf(v.z); o.w = f2bf(v.w);
        reinterpret_cast<ushort4*>(out)[i] = o;
    }
}

// Convert [W0|W1|loop] (fp32, row-major [KTOT x C] each) into bf16
// FRAGMENT-MAJOR panels for mfma_f32_16x16x32_bf16 B-operand:
// panel p = (sec*C+col)/64; within panel: idx = ((n16*(KTOT/8)+k/8)*16 + c)*8 + k%8
// where cin = (sec*C+col)%64, n16 = cin/16, c = cin%16.
template <int KTOT, int C>
__global__ void cvt_weights_kernel(const float* __restrict__ W,
                                   const float* __restrict__ loopw,
                                   ushort* __restrict__ dst) {
    const int TOT = 3 * C * KTOT;
    int q = blockIdx.x * blockDim.x + threadIdx.x;
    if (q >= TOT) return;
    int k = q / (3 * C), jgc = q % (3 * C);
    int sec = jgc / C, col = jgc % C;
    float v = (sec < 2) ? W[((size_t)sec * KTOT + k) * C + col]
                        : loopw[(size_t)k * C + col];
    int p = jgc >> 6, cin = jgc & 63;
    int di = p * (64 * KTOT) +
             (((cin >> 4) * (KTOT / 8) + (k >> 3)) * 16 + (cin & 15)) * 8 + (k & 7);
    dst[di] = f2bf(v);
}

// ---------------- MFMA node transform ----------------
// Y[:, 0:3C] = X @ [W0|W1|loop](+bias on loop sec), outputs routed to
// x0/x1/baseb (all bf16). BM=128, BN=64 (one panel), full-K single pass.
// 256 threads = 4 waves in 2x2; each wave owns 64x32 of the 128x64 tile.
template <int KTOT, int C>
__global__ __launch_bounds__(256, 4) void mfma_transform_kernel(
    const ushort* __restrict__ Xb,    // [M,KTOT] bf16
    const ushort* __restrict__ Wf,    // frag-major panels [3C/64][64*KTOT]
    const float*  __restrict__ bias,  // [C]
    ushort* __restrict__ x0, ushort* __restrict__ x1, ushort* __restrict__ baseb,
    int M) {
    constexpr int CPR = KTOT / 8;     // 16B chunks per row
    constexpr int NKB = KTOT / 32;    // K steps
    __shared__ ushort Al[128 * KTOT]; // fragment-major A tile

    const int row0 = blockIdx.x * 128;
    const int by   = blockIdx.y;
    const int sec  = (by * 64) / C;
    const int cof  = (by * 64) % C;

    const int wid  = threadIdx.x >> 6;
    const int wm   = wid >> 1, wn = wid & 1;
    const int lane = threadIdx.x & 63;

    // B fragments straight from global (frag-major, L2-resident)
    const ushort* Wp = Wf + (size_t)by * (64 * KTOT);
    bf16x8 bfrag[2][NKB];
#pragma unroll
    for (int j = 0; j < 2; ++j)
#pragma unroll
        for (int kb = 0; kb < NKB; ++kb)
            bfrag[j][kb] = *reinterpret_cast<const bf16x8*>(
                Wp + ((wn * 2 + j) * CPR + kb * 4) * 128 + lane * 8);

    // stage A tile into LDS, fragment-major (zero-fill OOB rows)
    constexpr int CH = 128 * CPR;     // total 16B chunks
    for (int ch = threadIdx.x; ch < CH; ch += 256) {
        int r = ch / CPR, kk8 = ch % CPR;
        int grow = row0 + r;
        uint4 v = make_uint4(0u, 0u, 0u, 0u);
        if (grow < M)
            v = *reinterpret_cast<const uint4*>(Xb + (size_t)grow * KTOT + kk8 * 8);
        int di = (((r >> 4) * CPR + kk8) * 16 + (r & 15)) * 8;
        *reinterpret_cast<uint4*>(&Al[di]) = v;
    }
    __syncthreads();

    f32x4 acc[4][2] = {};
#pragma unroll
    for (int kb = 0; kb < NKB; ++kb) {
        bf16x8 afrag[4];
#pragma unroll
        for (int i = 0; i < 4; ++i)
            afrag[i] = *reinterpret_cast<const bf16x8*>(
                &Al[((wm * 4 + i) * CPR + kb * 4) * 128 + lane * 8]);
#pragma unroll
        for (int i = 0; i < 4; ++i)
#pragma unroll
            for (int j = 0; j < 2; ++j)
                acc[i][j] = __builtin_amdgcn_mfma_f32_16x16x32_bf16(
                    afrag[i], bfrag[j][kb], acc[i][j], 0, 0, 0);
    }

    ushort* dst = (sec == 0) ? x0 : (sec == 1) ? x1 : baseb;
#pragma unroll
    for (int i = 0; i < 4; ++i) {
        int grow0 = row0 + (wm * 4 + i) * 16 + (lane >> 4) * 4;
#pragma unroll
        for (int j = 0; j < 2; ++j) {
            int scol = cof + wn * 32 + j * 16 + (lane & 15);
            float badd = (sec == 2) ? bias[scol] : 0.0f;
#pragma unroll
            for (int jj = 0; jj < 4; ++jj) {
                int grow = grow0 + jj;
                if (grow < M)
                    dst[(size_t)grow * C + scol] = f2bf(acc[i][j][jj] + badd);
            }
        }
    }
}

// ---------------- gather-aggregate (wide 16B/lane, multi-edge per wave) ----------------
// One wave per node. 64 lanes split into G = 64/LPR groups of LPR = C/8 lanes;
// each group gathers one edge's full row (8 bf16 = 16B per lane) per iteration,
// so G edges are in flight per wave. Cross-group butterfly reduce, then group 0
// adds base(+bias) and writes (bf16 hidden / fp32 final).
template <int C, bool RELU, bool OUTBF>
__global__ void gather_agg_kernel(const ushort* __restrict__ x0,
                                  const ushort* __restrict__ x1,
                                  const ushort* __restrict__ baseb,
                                  const int* __restrict__ off,
                                  const int* __restrict__ ent,
                                  ushort* __restrict__ outb,
                                  float* __restrict__ outf, int N) {
    constexpr int LPR = C / 8;        // lanes per row: 16 (C=128) / 8 (C=64)
    constexpr int G   = 64 / LPR;     // edge groups per wave: 4 / 8
    int wid  = (int)((blockIdx.x * blockDim.x + threadIdx.x) >> 6);
    int lane = threadIdx.x & 63;
    if (wid >= N) return;             // whole wave exits together
    const int g  = lane / LPR;
    const int li = lane % LPR;

    // base row (only group 0's copy is used) — issue early to hide latency
    uint4 bv = make_uint4(0u, 0u, 0u, 0u);
    if (g == 0)
        bv = *reinterpret_cast<const uint4*>(baseb + (size_t)wid * C + li * 8);

    float acc[8];
#pragma unroll
    for (int k = 0; k < 8; ++k) acc[k] = 0.0f;

    const int e1 = off[wid + 1];
    int j = off[wid] + g;
    int p = (j < e1) ? ent[j] : -1;
    while (p >= 0) {
        int jn = j + G;
        int pn = (jn < e1) ? ent[jn] : -1;   // prefetch next index
        const ushort* row = ((p & 1) ? x1 : x0) + (size_t)(p >> 1) * C + li * 8;
        uint4 v = *reinterpret_cast<const uint4*>(row);
        acc[0] += bfu_lo(v.x); acc[1] += bfu_hi(v.x);
        acc[2] += bfu_lo(v.y); acc[3] += bfu_hi(v.y);
        acc[4] += bfu_lo(v.z); acc[5] += bfu_hi(v.z);
        acc[6] += bfu_lo(v.w); acc[7] += bfu_hi(v.w);
        p = pn; j = jn;
    }

    // reduce across groups (lanes differing in bits >= log2(LPR))
#pragma unroll
    for (int m = LPR; m < 64; m <<= 1) {
#pragma unroll
        for (int k = 0; k < 8; ++k) acc[k] += __shfl_xor(acc[k], m, 64);
    }

    if (g == 0) {
        acc[0] += bfu_lo(bv.x); acc[1] += bfu_hi(bv.x);
        acc[2] += bfu_lo(bv.y); acc[3] += bfu_hi(bv.y);
        acc[4] += bfu_lo(bv.z); acc[5] += bfu_hi(bv.z);
        acc[6] += bfu_lo(bv.w); acc[7] += bfu_hi(bv.w);
        if (RELU) {
#pragma unroll
            for (int k = 0; k < 8; ++k) acc[k] = fmaxf(acc[k], 0.0f);
        }
        if (OUTBF) {
            uint4 o;
            o.x = (uint)f2bf(acc[0]) | ((uint)f2bf(acc[1]) << 16);
            o.y = (uint)f2bf(acc[2]) | ((uint)f2bf(acc[3]) << 16);
            o.z = (uint)f2bf(acc[4]) | ((uint)f2bf(acc[5]) << 16);
            o.w = (uint)f2bf(acc[6]) | ((uint)f2bf(acc[7]) << 16);
            *reinterpret_cast<uint4*>(outb + (size_t)wid * C + li * 8) = o;
        } else {
            float4 o0 = make_float4(acc[0], acc[1], acc[2], acc[3]);
            float4 o1 = make_float4(acc[4], acc[5], acc[6], acc[7]);
            float* dp = outf + (size_t)wid * C + li * 8;
            *reinterpret_cast<float4*>(dp)     = o0;
            *reinterpret_cast<float4*>(dp + 4) = o1;
        }
    }
}

extern "C" void kernel_launch(void* const* d_in, const int* in_sizes, int n_in,
                              void* d_out, int out_size, void* d_ws, size_t ws_size,
                              hipStream_t stream) {
    const float* feat  = (const float*)d_in[0];   // [N,64]
    const float* W1    = (const float*)d_in[1];   // [2,64,128]
    const float* loop1 = (const float*)d_in[2];   // [64,128]
    const float* b1    = (const float*)d_in[3];   // [128]
    const float* W2    = (const float*)d_in[4];   // [2,128,64]
    const float* loop2 = (const float*)d_in[5];   // [128,64]
    const float* b2    = (const float*)d_in[6];   // [64]
    const int*   src   = (const int*)d_in[7];     // [E]
    const int*   dst   = (const int*)d_in[8];     // [E]
    const int*   et    = (const int*)d_in[9];     // [E]
    float*       out   = (float*)d_out;           // [N,64]

    const int N = in_sizes[0] / N_IN;
    const int E = in_sizes[7];

    // ---- workspace layout ----
    char* wsb = (char*)d_ws;
    int* cnt  = (int*)wsb;            // [N]
    int* off  = cnt + N;              // [N+1]
    int* cur  = off + N + 1;          // [N]
    int* bsum = cur + N;              // [64]
    int* bx   = bsum + 64;            // [64]
    int* ent  = bx + 64;              // [E]
    size_t ibytes = (((size_t)(3 * N + 129 + E) * sizeof(int)) + 255) & ~(size_t)255;
    ushort* featb = (ushort*)(wsb + ibytes);            // [N,64]
    ushort* hb    = featb + (size_t)N * N_IN;           // [N,128]
    ushort* x0b   = hb    + (size_t)N * N_HID;          // [N,128] (L2: [N,64])
    ushort* x1b   = x0b   + (size_t)N * N_HID;          // [N,128] (L2: [N,64])
    ushort* baseb = x1b   + (size_t)N * N_HID;          // [N,128] (L2: [N,64])
    ushort* W1f   = baseb + (size_t)N * N_HID;          // [3*128*64]
    ushort* W2f   = W1f + 3 * N_HID * N_IN;             // [3*64*128]

    const int BLK  = 256;
    const int gE   = min((E + BLK - 1) / BLK, 2048);
    const int NB   = (N + 1023) / 1024;                 // scan chunks (<=64)
    const int mT   = (N + 127) / 128;                   // MFMA row tiles
    const int gAgg = (N * 64 + BLK - 1) / BLK;          // one wave per node
    const int gCvF = min((N * N_IN / 4 + BLK - 1) / BLK, 2048);

    // ---- CSR build (shared by both layers) ----
    hipMemsetAsync(cnt, 0, (size_t)N * sizeof(int), stream);
    hist_kernel<<<gE, BLK, 0, stream>>>(dst, cnt, E);
    scan_reduce_kernel<<<NB, 1024, 0, stream>>>(cnt, bsum, N);
    scan_top_kernel<<<1, 64, 0, stream>>>(bsum, bx, NB, off + N);
    scan_block_kernel<<<NB, 1024, 0, stream>>>(cnt, bx, off, cur, N);
    fill_kernel<<<gE, BLK, 0, stream>>>(src, dst, et, cur, ent, E);

    // ---- bf16 converts ----
    cvt_f32_bf16_kernel<<<gCvF, BLK, 0, stream>>>(feat, featb, N * N_IN / 4);
    cvt_weights_kernel<N_IN, N_HID><<<(3 * N_HID * N_IN + BLK - 1) / BLK, BLK, 0, stream>>>(
        W1, loop1, W1f);
    cvt_weights_kernel<N_HID, N_OUT><<<(3 * N_OUT * N_HID + BLK - 1) / BLK, BLK, 0, stream>>>(
        W2, loop2, W2f);

    // ---- layer 1 ----
    mfma_transform_kernel<N_IN, N_HID><<<dim3(mT, 3 * N_HID / 64), BLK, 0, stream>>>(
        featb, W1f, b1, x0b, x1b, baseb, N);
    gather_agg_kernel<N_HID, true, true><<<gAgg, BLK, 0, stream>>>(
        x0b, x1b, baseb, off, ent, hb, nullptr, N);

    // ---- layer 2 ----
    mfma_transform_kernel<N_HID, N_OUT><<<dim3(mT, 3 * N_OUT / 64), BLK, 0, stream>>>(
        hb, W2f, b2, x0b, x1b, baseb, N);
    gather_agg_kernel<N_OUT, false, false><<<gAgg, BLK, 0, stream>>>(
        x0b, x1b, baseb, off, ent, nullptr, out, N);
}

// Round 15
// 241.493 us; speedup vs baseline: 10.8679x; 1.1632x over previous
//
#include <hip/hip_runtime.h>
#include <hip/hip_bf16.h>

// 2-layer R-GCN (NUM_RELS=2). bf16 MFMA transforms + bf16 wide-gather pipeline,
// fp32 accumulation everywhere. Atomic-free dst-CSR: rank captured in hist pass,
// fill is pure scatter (no atomics). feat fp32->bf16 fused into layer-1 staging.
//  N=50000, E=800000, feats 64 -> 128 -> 64.
//  layer(x,W,loop,b): agg = segsum((etype==0 ? x@W0 : x@W1)[src], dst) + x@loop + b
//  out = layer2(relu(layer1(feat)))

#define N_IN   64
#define N_HID  128
#define N_OUT  64

typedef __attribute__((ext_vector_type(8))) short  bf16x8;
typedef __attribute__((ext_vector_type(4))) float  f32x4;

__device__ __forceinline__ ushort f2bf(float f) {   // RNE
    uint u = __float_as_uint(f);
    u += 0x7FFFu + ((u >> 16) & 1u);
    return (ushort)(u >> 16);
}
__device__ __forceinline__ float bf2f(ushort h) {
    return __uint_as_float(((uint)h) << 16);
}
// unpack a uint holding 2 bf16: lo = bits[15:0], hi = bits[31:16]
__device__ __forceinline__ float bfu_lo(uint u) { return __uint_as_float(u << 16); }
__device__ __forceinline__ float bfu_hi(uint u) { return __uint_as_float(u & 0xFFFF0000u); }

// ---------------- CSR build ----------------
// Pass 1: histogram AND per-edge stable rank (atomicAdd's return value).
__global__ void hist_rank_kernel(const int* __restrict__ dst, int* __restrict__ cnt,
                                 int* __restrict__ rank, int E) {
    for (int e = blockIdx.x * blockDim.x + threadIdx.x; e < E;
         e += gridDim.x * blockDim.x)
        rank[e] = atomicAdd(&cnt[dst[e]], 1);
}

__global__ void scan_reduce_kernel(const int* __restrict__ cnt, int* __restrict__ bsum, int N) {
    __shared__ int s[1024];
    int i = blockIdx.x * 1024 + threadIdx.x;
    s[threadIdx.x] = (i < N) ? cnt[i] : 0;
    __syncthreads();
    for (int st = 512; st > 0; st >>= 1) {
        if ((int)threadIdx.x < st) s[threadIdx.x] += s[threadIdx.x + st];
        __syncthreads();
    }
    if (threadIdx.x == 0) bsum[blockIdx.x] = s[0];
}

// 64-thread exclusive scan of bsum[0..NB) (NB <= 64); total -> *offN
__global__ void scan_top_kernel(const int* __restrict__ bsum, int* __restrict__ bx,
                                int NB, int* __restrict__ offN) {
    int l = threadIdx.x;
    int v = (l < NB) ? bsum[l] : 0;
    int x = v;
    for (int s = 1; s < 64; s <<= 1) {
        int t = __shfl_up(x, (unsigned)s, 64);
        if (l >= s) x += t;
    }
    if (l < NB) bx[l] = x - v;
    if (l == 63) *offN = x;
}

__global__ void scan_block_kernel(const int* __restrict__ cnt, const int* __restrict__ bx,
                                  int* __restrict__ off, int N) {
    __shared__ int s[1024];
    int i = blockIdx.x * 1024 + threadIdx.x;
    int v = (i < N) ? cnt[i] : 0;
    s[threadIdx.x] = v;
    __syncthreads();
    for (int st = 1; st < 1024; st <<= 1) {
        int t = ((int)threadIdx.x >= st) ? s[threadIdx.x - st] : 0;
        __syncthreads();
        s[threadIdx.x] += t;
        __syncthreads();
    }
    if (i < N) off[i] = bx[blockIdx.x] + s[threadIdx.x] - v;
}

// Pass 2: atomic-free scatter using precomputed off + rank.
__global__ void fill_kernel(const int* __restrict__ src, const int* __restrict__ dst,
                            const int* __restrict__ et, const int* __restrict__ off,
                            const int* __restrict__ rank, int* __restrict__ ent, int E) {
    for (int e = blockIdx.x * blockDim.x + threadIdx.x; e < E;
         e += gridDim.x * blockDim.x)
        ent[off[dst[e]] + rank[e]] = (src[e] << 1) | et[e];
}

// Convert [W0|W1|loop] (fp32, row-major [KTOT x C] each) into bf16
// FRAGMENT-MAJOR panels for mfma_f32_16x16x32_bf16 B-operand:
// panel p = (sec*C+col)/64; within panel: idx = ((n16*(KTOT/8)+k/8)*16 + c)*8 + k%8
// where cin = (sec*C+col)%64, n16 = cin/16, c = cin%16.
template <int KTOT, int C>
__global__ void cvt_weights_kernel(const float* __restrict__ W,
                                   const float* __restrict__ loopw,
                                   ushort* __restrict__ dst) {
    const int TOT = 3 * C * KTOT;
    int q = blockIdx.x * blockDim.x + threadIdx.x;
    if (q >= TOT) return;
    int k = q / (3 * C), jgc = q % (3 * C);
    int sec = jgc / C, col = jgc % C;
    float v = (sec < 2) ? W[((size_t)sec * KTOT + k) * C + col]
                        : loopw[(size_t)k * C + col];
    int p = jgc >> 6, cin = jgc & 63;
    int di = p * (64 * KTOT) +
             (((cin >> 4) * (KTOT / 8) + (k >> 3)) * 16 + (cin & 15)) * 8 + (k & 7);
    dst[di] = f2bf(v);
}

// ---------------- MFMA node transform ----------------
// Y[:, 0:3C] = X @ [W0|W1|loop](+bias on loop sec), outputs routed to
// x0/x1/baseb (all bf16). BM=128, BN=64 (one panel), full-K single pass.
// 256 threads = 4 waves in 2x2; each wave owns 64x32 of the 128x64 tile.
// INF32: X is fp32 (layer-1 feat) — convert during LDS staging.
template <int KTOT, int C, bool INF32>
__global__ __launch_bounds__(256, 4) void mfma_transform_kernel(
    const void* __restrict__ Xsrc,    // [M,KTOT] bf16 or fp32
    const ushort* __restrict__ Wf,    // frag-major panels [3C/64][64*KTOT]
    const float*  __restrict__ bias,  // [C]
    ushort* __restrict__ x0, ushort* __restrict__ x1, ushort* __restrict__ baseb,
    int M) {
    constexpr int CPR = KTOT / 8;     // 16B (8-elem) chunks per row
    constexpr int NKB = KTOT / 32;    // K steps
    __shared__ ushort Al[128 * KTOT]; // fragment-major A tile

    const int row0 = blockIdx.x * 128;
    const int by   = blockIdx.y;
    const int sec  = (by * 64) / C;
    const int cof  = (by * 64) % C;

    const int wid  = threadIdx.x >> 6;
    const int wm   = wid >> 1, wn = wid & 1;
    const int lane = threadIdx.x & 63;

    // B fragments straight from global (frag-major, L2-resident)
    const ushort* Wp = Wf + (size_t)by * (64 * KTOT);
    bf16x8 bfrag[2][NKB];
#pragma unroll
    for (int j = 0; j < 2; ++j)
#pragma unroll
        for (int kb = 0; kb < NKB; ++kb)
            bfrag[j][kb] = *reinterpret_cast<const bf16x8*>(
                Wp + ((wn * 2 + j) * CPR + kb * 4) * 128 + lane * 8);

    // stage A tile into LDS, fragment-major (zero-fill OOB rows)
    constexpr int CH = 128 * CPR;     // total 8-elem chunks
    for (int ch = threadIdx.x; ch < CH; ch += 256) {
        int r = ch / CPR, kk8 = ch % CPR;
        int grow = row0 + r;
        uint4 v = make_uint4(0u, 0u, 0u, 0u);
        if (grow < M) {
            if constexpr (INF32) {
                const float* Xf = (const float*)Xsrc + (size_t)grow * KTOT + kk8 * 8;
                float4 a = *reinterpret_cast<const float4*>(Xf);
                float4 b = *reinterpret_cast<const float4*>(Xf + 4);
                v.x = (uint)f2bf(a.x) | ((uint)f2bf(a.y) << 16);
                v.y = (uint)f2bf(a.z) | ((uint)f2bf(a.w) << 16);
                v.z = (uint)f2bf(b.x) | ((uint)f2bf(b.y) << 16);
                v.w = (uint)f2bf(b.z) | ((uint)f2bf(b.w) << 16);
            } else {
                v = *reinterpret_cast<const uint4*>(
                    (const ushort*)Xsrc + (size_t)grow * KTOT + kk8 * 8);
            }
        }
        int di = (((r >> 4) * CPR + kk8) * 16 + (r & 15)) * 8;
        *reinterpret_cast<uint4*>(&Al[di]) = v;
    }
    __syncthreads();

    f32x4 acc[4][2] = {};
#pragma unroll
    for (int kb = 0; kb < NKB; ++kb) {
        bf16x8 afrag[4];
#pragma unroll
        for (int i = 0; i < 4; ++i)
            afrag[i] = *reinterpret_cast<const bf16x8*>(
                &Al[((wm * 4 + i) * CPR + kb * 4) * 128 + lane * 8]);
#pragma unroll
        for (int i = 0; i < 4; ++i)
#pragma unroll
            for (int j = 0; j < 2; ++j)
                acc[i][j] = __builtin_amdgcn_mfma_f32_16x16x32_bf16(
                    afrag[i], bfrag[j][kb], acc[i][j], 0, 0, 0);
    }

    ushort* dst = (sec == 0) ? x0 : (sec == 1) ? x1 : baseb;
#pragma unroll
    for (int i = 0; i < 4; ++i) {
        int grow0 = row0 + (wm * 4 + i) * 16 + (lane >> 4) * 4;
#pragma unroll
        for (int j = 0; j < 2; ++j) {
            int scol = cof + wn * 32 + j * 16 + (lane & 15);
            float badd = (sec == 2) ? bias[scol] : 0.0f;
#pragma unroll
            for (int jj = 0; jj < 4; ++jj) {
                int grow = grow0 + jj;
                if (grow < M)
                    dst[(size_t)grow * C + scol] = f2bf(acc[i][j][jj] + badd);
            }
        }
    }
}

// ---------------- gather-aggregate (wide 16B/lane, multi-edge per wave) ----------------
// One wave per node. 64 lanes split into G = 64/LPR groups of LPR = C/8 lanes;
// each group gathers one edge's full row (8 bf16 = 16B per lane) per iteration,
// so G edges are in flight per wave. Cross-group butterfly reduce, then group 0
// adds base(+bias) and writes (bf16 hidden / fp32 final).
template <int C, bool RELU, bool OUTBF>
__global__ void gather_agg_kernel(const ushort* __restrict__ x0,
                                  const ushort* __restrict__ x1,
                                  const ushort* __restrict__ baseb,
                                  const int* __restrict__ off,
                                  const int* __restrict__ ent,
                                  ushort* __restrict__ outb,
                                  float* __restrict__ outf, int N) {
    constexpr int LPR = C / 8;        // lanes per row: 16 (C=128) / 8 (C=64)
    constexpr int G   = 64 / LPR;     // edge groups per wave: 4 / 8
    int wid  = (int)((blockIdx.x * blockDim.x + threadIdx.x) >> 6);
    int lane = threadIdx.x & 63;
    if (wid >= N) return;             // whole wave exits together
    const int g  = lane / LPR;
    const int li = lane % LPR;

    // base row (only group 0's copy is used) — issue early to hide latency
    uint4 bv = make_uint4(0u, 0u, 0u, 0u);
    if (g == 0)
        bv = *reinterpret_cast<const uint4*>(baseb + (size_t)wid * C + li * 8);

    float acc[8];
#pragma unroll
    for (int k = 0; k < 8; ++k) acc[k] = 0.0f;

    const int e1 = off[wid + 1];
    int j = off[wid] + g;
    int p = (j < e1) ? ent[j] : -1;
    while (p >= 0) {
        int jn = j + G;
        int pn = (jn < e1) ? ent[jn] : -1;   // prefetch next index
        const ushort* row = ((p & 1) ? x1 : x0) + (size_t)(p >> 1) * C + li * 8;
        uint4 v = *reinterpret_cast<const uint4*>(row);
        acc[0] += bfu_lo(v.x); acc[1] += bfu_hi(v.x);
        acc[2] += bfu_lo(v.y); acc[3] += bfu_hi(v.y);
        acc[4] += bfu_lo(v.z); acc[5] += bfu_hi(v.z);
        acc[6] += bfu_lo(v.w); acc[7] += bfu_hi(v.w);
        p = pn; j = jn;
    }

    // reduce across groups (lanes differing in bits >= log2(LPR))
#pragma unroll
    for (int m = LPR; m < 64; m <<= 1) {
#pragma unroll
        for (int k = 0; k < 8; ++k) acc[k] += __shfl_xor(acc[k], m, 64);
    }

    if (g == 0) {
        acc[0] += bfu_lo(bv.x); acc[1] += bfu_hi(bv.x);
        acc[2] += bfu_lo(bv.y); acc[3] += bfu_hi(bv.y);
        acc[4] += bfu_lo(bv.z); acc[5] += bfu_hi(bv.z);
        acc[6] += bfu_lo(bv.w); acc[7] += bfu_hi(bv.w);
        if (RELU) {
#pragma unroll
            for (int k = 0; k < 8; ++k) acc[k] = fmaxf(acc[k], 0.0f);
        }
        if (OUTBF) {
            uint4 o;
            o.x = (uint)f2bf(acc[0]) | ((uint)f2bf(acc[1]) << 16);
            o.y = (uint)f2bf(acc[2]) | ((uint)f2bf(acc[3]) << 16);
            o.z = (uint)f2bf(acc[4]) | ((uint)f2bf(acc[5]) << 16);
            o.w = (uint)f2bf(acc[6]) | ((uint)f2bf(acc[7]) << 16);
            *reinterpret_cast<uint4*>(outb + (size_t)wid * C + li * 8) = o;
        } else {
            float4 o0 = make_float4(acc[0], acc[1], acc[2], acc[3]);
            float4 o1 = make_float4(acc[4], acc[5], acc[6], acc[7]);
            float* dp = outf + (size_t)wid * C + li * 8;
            *reinterpret_cast<float4*>(dp)     = o0;
            *reinterpret_cast<float4*>(dp + 4) = o1;
        }
    }
}

extern "C" void kernel_launch(void* const* d_in, const int* in_sizes, int n_in,
                              void* d_out, int out_size, void* d_ws, size_t ws_size,
                              hipStream_t stream) {
    const float* feat  = (const float*)d_in[0];   // [N,64]
    const float* W1    = (const float*)d_in[1];   // [2,64,128]
    const float* loop1 = (const float*)d_in[2];   // [64,128]
    const float* b1    = (const float*)d_in[3];   // [128]
    const float* W2    = (const float*)d_in[4];   // [2,128,64]
    const float* loop2 = (const float*)d_in[5];   // [128,64]
    const float* b2    = (const float*)d_in[6];   // [64]
    const int*   src   = (const int*)d_in[7];     // [E]
    const int*   dst   = (const int*)d_in[8];     // [E]
    const int*   et    = (const int*)d_in[9];     // [E]
    float*       out   = (float*)d_out;           // [N,64]

    const int N = in_sizes[0] / N_IN;
    const int E = in_sizes[7];

    // ---- workspace layout ----
    char* wsb = (char*)d_ws;
    int* cnt  = (int*)wsb;            // [N]
    int* off  = cnt + N;              // [N+1]
    int* bsum = off + N + 1;          // [64]
    int* bx   = bsum + 64;            // [64]
    int* rank = bx + 64;              // [E]
    int* ent  = rank + E;             // [E]
    size_t ibytes = (((size_t)(2 * N + 129 + 2 * E) * sizeof(int)) + 255) & ~(size_t)255;
    ushort* hb    = (ushort*)(wsb + ibytes);            // [N,128]
    ushort* x0b   = hb    + (size_t)N * N_HID;          // [N,128] (L2: [N,64])
    ushort* x1b   = x0b   + (size_t)N * N_HID;          // [N,128] (L2: [N,64])
    ushort* baseb = x1b   + (size_t)N * N_HID;          // [N,128] (L2: [N,64])
    ushort* W1f   = baseb + (size_t)N * N_HID;          // [3*128*64]
    ushort* W2f   = W1f + 3 * N_HID * N_IN;             // [3*64*128]

    const int BLK  = 256;
    const int gE   = min((E + BLK - 1) / BLK, 2048);
    const int NB   = (N + 1023) / 1024;                 // scan chunks (<=64)
    const int mT   = (N + 127) / 128;                   // MFMA row tiles
    const int gAgg = (N * 64 + BLK - 1) / BLK;          // one wave per node

    // ---- CSR build (shared by both layers) ----
    hipMemsetAsync(cnt, 0, (size_t)N * sizeof(int), stream);
    hist_rank_kernel<<<gE, BLK, 0, stream>>>(dst, cnt, rank, E);
    scan_reduce_kernel<<<NB, 1024, 0, stream>>>(cnt, bsum, N);
    scan_top_kernel<<<1, 64, 0, stream>>>(bsum, bx, NB, off + N);
    scan_block_kernel<<<NB, 1024, 0, stream>>>(cnt, bx, off, N);
    fill_kernel<<<gE, BLK, 0, stream>>>(src, dst, et, off, rank, ent, E);

    // ---- weight converts ----
    cvt_weights_kernel<N_IN, N_HID><<<(3 * N_HID * N_IN + BLK - 1) / BLK, BLK, 0, stream>>>(
        W1, loop1, W1f);
    cvt_weights_kernel<N_HID, N_OUT><<<(3 * N_OUT * N_HID + BLK - 1) / BLK, BLK, 0, stream>>>(
        W2, loop2, W2f);

    // ---- layer 1 (feat fp32 read directly; cvt fused into staging) ----
    mfma_transform_kernel<N_IN, N_HID, true><<<dim3(mT, 3 * N_HID / 64), BLK, 0, stream>>>(
        feat, W1f, b1, x0b, x1b, baseb, N);
    gather_agg_kernel<N_HID, true, true><<<gAgg, BLK, 0, stream>>>(
        x0b, x1b, baseb, off, ent, hb, nullptr, N);

    // ---- layer 2 ----
    mfma_transform_kernel<N_HID, N_OUT, false><<<dim3(mT, 3 * N_OUT / 64), BLK, 0, stream>>>(
        hb, W2f, b2, x0b, x1b, baseb, N);
    gather_agg_kernel<N_OUT, false, false><<<gAgg, BLK, 0, stream>>>(
        x0b, x1b, baseb, off, ent, nullptr, out, N);
}